// Round 19
// baseline (126.189 us; speedup 1.0000x reference)
//
#include <hip/hip_runtime.h>
#include <hip/hip_bf16.h>
#include <math.h>

typedef __bf16 bf16;
typedef __bf16 bf16x4 __attribute__((ext_vector_type(4)));
typedef __bf16 bf16x8 __attribute__((ext_vector_type(8)));
typedef float  f32x4  __attribute__((ext_vector_type(4)));
typedef float  f32x16 __attribute__((ext_vector_type(16)));

#define S_LEN 2048
#define EMB   2048
#define NH    16
#define NKV   4
#define HD    128
#define FQKV  3072  /* NH*HD + 2*NKV*HD */

__device__ __forceinline__ f32x4 mfma16(bf16x8 a, bf16x8 b, f32x4 c) {
  return __builtin_amdgcn_mfma_f32_16x16x32_bf16(a, b, c, 0, 0, 0);
}
__device__ __forceinline__ f32x16 mfma32(bf16x8 a, bf16x8 b, f32x16 c) {
  return __builtin_amdgcn_mfma_f32_32x32x16_bf16(a, b, c, 0, 0, 0);
}
__device__ __forceinline__ f32x16 zero16() {
  f32x16 v;
#pragma unroll
  for (int i = 0; i < 16; ++i) v[i] = 0.f;
  return v;
}

// ---------------- RoPE cos/sin table: tab[spos][f] = (cos, sin), f in [0,64) ----------------
__global__ void rope_init(float2* __restrict__ rt) {
  const int idx = blockIdx.x * blockDim.x + threadIdx.x;   // 131072 entries
  const int spos = idx >> 6, f = idx & 63;
  const float inv = exp2f(-(float)f * (13.287712379549449f / 64.0f)); // 10000^(-f/64)
  float s, c;
  sincosf((float)spos * inv, &s, &c);
  rt[idx] = make_float2(c, s);
}

// ---------------- fused f32 -> bf16 convert for all three inputs ----------------
__global__ void cvt3_kernel(const float* __restrict__ a, bf16* __restrict__ ab, int na4,
                            const float* __restrict__ b, bf16* __restrict__ bb, int nb4,
                            const float* __restrict__ c, bf16* __restrict__ cb, int nc4) {
  int i = blockIdx.x * blockDim.x + threadIdx.x;
  const int stride = gridDim.x * blockDim.x;
  const int total = na4 + nb4 + nc4;
  for (; i < total; i += stride) {
    const float* src; bf16* dst; int j = i;
    if (j < na4)            { src = a; dst = ab; }
    else if (j < na4 + nb4) { j -= na4; src = b; dst = bb; }
    else                    { j -= na4 + nb4; src = c; dst = cb; }
    float4 v = reinterpret_cast<const float4*>(src)[j];
    bf16x4 o;
    o[0] = (bf16)v.x; o[1] = (bf16)v.y; o[2] = (bf16)v.z; o[3] = (bf16)v.w;
    reinterpret_cast<bf16x4*>(dst)[j] = o;
  }
}

// ---------------- GEMM: C[M][N] = A[M][K] * B[N][K]^T, tile BM x BN ----------------
// BM=64,BN=128 mode 0 (QKV): 768 blocks = exactly 3/CU. Fused RoPE/split epilogue,
//   Q/K/V in fragment-ready TILED layouts; indices derived from absolute spos.
// BM=128,BN=64 mode 1 (dense): 512 blocks = 2/CU, plain f32 store.
template<int BM, int BN>
__global__ __launch_bounds__(256, (BM == 64 ? 3 : 2)) void gemm_bt(
    const bf16* __restrict__ A, const bf16* __restrict__ B,
    int M, int N, int K, int mode,
    bf16* __restrict__ qb, bf16* __restrict__ kb, bf16* __restrict__ vtb,
    float* __restrict__ outf, const float2* __restrict__ rt)
{
  constexpr int NFR = BN / 16;      // N fragments per wave
  constexpr int MR  = BM / 4;       // rows per wave
  constexpr int MT  = MR / 16;      // M fragments per wave
  __shared__ __align__(16) bf16 As[BM * 64];
  __shared__ __align__(16) bf16 Bs[BN * 64];
  const int tid = threadIdx.x;
  const int w  = tid >> 6;
  const int l  = tid & 63;
  const int li = l & 15, lh = l >> 4;
  const int m0 = blockIdx.y * BM, n0 = blockIdx.x * BN;

  f32x4 acc[MT][NFR];
#pragma unroll
  for (int i = 0; i < MT; ++i)
#pragma unroll
    for (int j = 0; j < NFR; ++j) acc[i][j] = f32x4{0.f, 0.f, 0.f, 0.f};

  const int srow = l >> 3;   // row within an 8-row staging group
  const int schk = l & 7;    // 16B chunk within a 64-col row

  for (int k0 = 0; k0 < K; k0 += 64) {
#pragma unroll
    for (int i = 0; i < BM / 32; ++i) {    // A: BM rows
      const int row = i * 32 + w * 8 + srow;
      const int sch = schk ^ (row & 7);
      const bf16* ga = A + (size_t)(m0 + row) * K + (k0 + sch * 8);
      bf16* la = As + (i * 32 + w * 8) * 64;
      __builtin_amdgcn_global_load_lds((const __attribute__((address_space(1))) void*)ga,
                                       (__attribute__((address_space(3))) void*)la, 16, 0, 0);
    }
#pragma unroll
    for (int i = 0; i < BN / 32; ++i) {    // B: BN rows
      const int row = i * 32 + w * 8 + srow;
      const int sch = schk ^ (row & 7);
      const bf16* gb = B + (size_t)(n0 + row) * K + (k0 + sch * 8);
      bf16* lb = Bs + (i * 32 + w * 8) * 64;
      __builtin_amdgcn_global_load_lds((const __attribute__((address_space(1))) void*)gb,
                                       (__attribute__((address_space(3))) void*)lb, 16, 0, 0);
    }
    __syncthreads();
#pragma unroll
    for (int kc = 0; kc < 2; ++kc) {
      bf16x8 afr[MT], bfr[NFR];
#pragma unroll
      for (int mt = 0; mt < MT; ++mt) {
        const int mr = w * MR + mt * 16 + li;
        const int c  = (kc * 4 + lh) ^ (mr & 7);
        afr[mt] = *reinterpret_cast<const bf16x8*>((const char*)As + mr * 128 + c * 16);
      }
#pragma unroll
      for (int nt = 0; nt < NFR; ++nt) {
        const int nr = nt * 16 + li;
        const int c  = (kc * 4 + lh) ^ (nr & 7);
        bfr[nt] = *reinterpret_cast<const bf16x8*>((const char*)Bs + nr * 128 + c * 16);
      }
#pragma unroll
      for (int mt = 0; mt < MT; ++mt)
#pragma unroll
        for (int nt = 0; nt < NFR; ++nt)
          acc[mt][nt] = mfma16(afr[mt], bfr[nt], acc[mt][nt]);
    }
    __syncthreads();
  }

  // ---- epilogue ----
  if (mode == 1) {
#pragma unroll
    for (int mt = 0; mt < MT; ++mt)
#pragma unroll
      for (int nt = 0; nt < NFR; ++nt)
#pragma unroll
        for (int r = 0; r < 4; ++r) {
          const int sr = m0 + w * MR + mt * 16 + lh * 4 + r;
          const int sc = n0 + nt * 16 + li;
          outf[(size_t)sr * N + sc] = acc[mt][nt][r];
        }
  } else {
    int seg, hh;
    if (n0 < NH * HD)             { seg = 0; hh = n0 >> 7; }
    else if (n0 < (NH + NKV) * HD){ seg = 1; hh = (n0 - NH * HD) >> 7; }
    else                          { seg = 2; hh = (n0 - (NH + NKV) * HD) >> 7; }

    if (seg == 2) {
      // V tiled store; all indices from absolute spos (S0 = spos of r=0).
#pragma unroll
      for (int mt = 0; mt < MT; ++mt) {
        const int S0 = m0 + w * MR + mt * 16 + lh * 4;
        const int T  = S0 >> 5;
        const int qp = (S0 & 31) >> 2;
        const int jj = (qp >> 2) & 1, hiv = qp & 1, ebase = 4 * ((qp >> 1) & 1);
        bf16* vdst = vtb + (size_t)hh * S_LEN * HD + (size_t)T * 4096;
#pragma unroll
        for (int nt = 0; nt < 8; ++nt) {
          const int dt = nt >> 1;
          const int lqv = (nt & 1) * 16 + li;
          bf16x4 pk;
#pragma unroll
          for (int r = 0; r < 4; ++r) pk[r] = (bf16)acc[mt][nt][r];
          *reinterpret_cast<bf16x4*>(
              vdst + ((dt * 2 + jj) * 2 + hiv) * 256 + lqv * 8 + ebase) = pk;
        }
      }
    } else {  // Q or K: RoPE (table-driven; 1/sqrt(D) folded into Q), tiled store
      bf16* dstb = (seg == 0) ? (qb + (size_t)hh * S_LEN * HD)
                              : (kb + (size_t)hh * S_LEN * HD);
      const float qscale = (seg == 0) ? 0.08838834764831845f : 1.0f;
      const int hi2 = li >> 3, e2 = li & 7;
#pragma unroll
      for (int mt = 0; mt < MT; ++mt)
#pragma unroll
        for (int r = 0; r < 4; ++r) {
          const int spos = m0 + w * MR + mt * 16 + lh * 4 + r;
          const int T    = spos >> 5;
          const int lqr  = spos & 31;
          bf16* dst = dstb + (size_t)T * 4096;
          float cs[4], sn[4];
#pragma unroll
          for (int j = 0; j < 4; ++j) {
            const float2 t = rt[spos * 64 + j * 16 + li];
            cs[j] = t.x; sn[j] = t.y;
          }
#pragma unroll
          for (int nt = 0; nt < 8; ++nt) {
            const int j = nt & 3;
            const float x = acc[mt][nt][r];
            const float prt = acc[mt][nt ^ 4][r];
            const float rot = (nt < 4) ? -prt : prt;
            const float y = (x * cs[j] + rot * sn[j]) * qscale;
            dst[(nt * 2 + hi2) * 256 + lqr * 8 + e2] = (bf16)y;
          }
        }
    }
  }
}

// ---------------- flash attention: 3-wave blocks + dispatcher refill pool ----------------
// 1024 blocks x 192 thr (3 waves). Block (qt = 63 - b/16, h = b&15), longest
// first. Waves split KV 3-way by parity (wave w: tiles t = w, w+3, ...), each
// with a PRIVATE 16KB K/V buffer and the counted split-stage pipeline
// (vmcnt(8) -> read K, lgkm(0) -> refill K -> QK^T -> vmcnt(8) -> read V,
// lgkm(0) -> refill V -> softmax+PV). LDS 48KB -> 3 blocks/CU resident = 9
// waves/CU, grid 1024 > 768 resident -> 256-block backlog refills CUs as short
// blocks retire (kills the drain that capped r13 at 4.3 waves/CU). Fixed-m
// softmax; 3-way plain-sum merge through aliased Obf.
__global__ __launch_bounds__(192, 2) void attn_kernel(
    const bf16* __restrict__ qb, const bf16* __restrict__ kb, const bf16* __restrict__ vtb,
    bf16* __restrict__ ctx)
{
  __shared__ __align__(16) char smem[49152];   // 3 x 16KB wave K/V bufs; aliased Obf/Lg

  const int tid = threadIdx.x;
  const int ws = tid >> 6;      // wave id = kv parity (0..2)
  const int l  = tid & 63;
  const int lq = l & 31;
  const int hi = l >> 5;
  const int b  = (int)blockIdx.x;
  const int qt = 63 - (b >> 4);   // longest first (dispatch order ~ blockIdx)
  const int h  = b & 15;
  const int q0 = qt * 32;
  const int kh = h >> 2;

  bf16* Kbuf = (bf16*)(smem + ws * 16384);          // 8 KB
  bf16* Vbuf = (bf16*)(smem + ws * 16384 + 8192);   // 8 KB
  float* Obf = (float*)smem;                        // [32][129] f32, epilogue only

  const bf16* Qh = qb + (size_t)h * S_LEN * HD;
  const bf16* Kh = kb + (size_t)kh * S_LEN * HD;
  const bf16* Vh = vtb + (size_t)kh * S_LEN * HD;

  const float L2E = 1.4426950408889634f;
  const float BIG = -3.0e38f;

  // hoist Q fragments (coalesced 1KB loads from tiled layout)
  const bf16* qtile = Qh + (size_t)qt * 4096;
  bf16x8 qfr[8];
#pragma unroll
  for (int kc = 0; kc < 8; ++kc)
    qfr[kc] = *reinterpret_cast<const bf16x8*>(qtile + (kc * 2 + hi) * 256 + lq * 8);

  f32x16 o[4];
#pragma unroll
  for (int dt = 0; dt < 4; ++dt) o[dt] = zero16();
  float lrow = 0.f;

  // ---- prologue: stage this wave's first tile (K then V: FIFO order) ----
  if (ws <= qt) {
    const bf16* ksrc = Kh + (size_t)ws * 4096 + l * 8;
    const bf16* vsrc = Vh + (size_t)ws * 4096 + l * 8;
#pragma unroll
    for (int c = 0; c < 8; ++c)
      __builtin_amdgcn_global_load_lds(
          (const __attribute__((address_space(1))) void*)(ksrc + c * 512),
          (__attribute__((address_space(3))) void*)(Kbuf + c * 512), 16, 0, 0);
#pragma unroll
    for (int c = 0; c < 8; ++c)
      __builtin_amdgcn_global_load_lds(
          (const __attribute__((address_space(1))) void*)(vsrc + c * 512),
          (__attribute__((address_space(3))) void*)(Vbuf + c * 512), 16, 0, 0);
  }

  for (int t = ws; t <= qt; t += 3) {
    const int tn = (t + 3 <= qt) ? (t + 3) : qt;   // clamped prefetch (uniform counts)
    // ---- K stage: wait K (V still in flight), read frags, refill K ----
    asm volatile("s_waitcnt vmcnt(8)" ::: "memory");
    __builtin_amdgcn_sched_barrier(0);
    bf16x8 kf[8];
#pragma unroll
    for (int kc = 0; kc < 8; ++kc)
      kf[kc] = *reinterpret_cast<const bf16x8*>(Kbuf + (kc * 2 + hi) * 256 + lq * 8);
    asm volatile("s_waitcnt lgkmcnt(0)" ::: "memory");
    __builtin_amdgcn_sched_barrier(0);
    {
      const bf16* ksrc = Kh + (size_t)tn * 4096 + l * 8;
#pragma unroll
      for (int c = 0; c < 8; ++c)
        __builtin_amdgcn_global_load_lds(
            (const __attribute__((address_space(1))) void*)(ksrc + c * 512),
            (__attribute__((address_space(3))) void*)(Kbuf + c * 512), 16, 0, 0);
    }
    // ---- QK^T: S^T[kv][q], two chains of 4 (covers V's remaining latency) ----
    f32x16 sa = zero16(), sb = zero16();
    __builtin_amdgcn_s_setprio(1);
#pragma unroll
    for (int kc = 0; kc < 4; ++kc) {
      sa = mfma32(kf[kc], qfr[kc], sa);
      sb = mfma32(kf[kc + 4], qfr[kc + 4], sb);
    }
    __builtin_amdgcn_s_setprio(0);
    f32x16 s = sa + sb;
    // ---- V stage: wait V (next-K in flight), read frags, refill V ----
    asm volatile("s_waitcnt vmcnt(8)" ::: "memory");
    __builtin_amdgcn_sched_barrier(0);
    bf16x8 va[8];
#pragma unroll
    for (int sv = 0; sv < 8; ++sv)
      va[sv] = *reinterpret_cast<const bf16x8*>(Vbuf + (sv * 2 + hi) * 256 + lq * 8);
    asm volatile("s_waitcnt lgkmcnt(0)" ::: "memory");
    __builtin_amdgcn_sched_barrier(0);
    {
      const bf16* vsrc = Vh + (size_t)tn * 4096 + l * 8;
#pragma unroll
      for (int c = 0; c < 8; ++c)
        __builtin_amdgcn_global_load_lds(
            (const __attribute__((address_space(1))) void*)(vsrc + c * 512),
            (__attribute__((address_space(3))) void*)(Vbuf + c * 512), 16, 0, 0);
    }
    // ---- causal mask (diagonal tile only) ----
    if (t == qt) {
      const int q = q0 + lq;
#pragma unroll
      for (int r = 0; r < 16; ++r) {
        const int kvv = (r & 3) + 8 * (r >> 2) + 4 * hi;
        if (t * 32 + kvv > q) s[r] = BIG;
      }
    }
    // ---- fixed-m softmax: P = exp2(s*L2E), no max tracking, no rescale ----
    bf16x8 pb0, pb1;
    float tsum = 0.f;
#pragma unroll
    for (int r = 0; r < 8; ++r) {
      const float pv = exp2f(s[r] * L2E);
      tsum += pv; pb0[r] = (bf16)pv;
    }
#pragma unroll
    for (int r = 0; r < 8; ++r) {
      const float pv = exp2f(s[8 + r] * L2E);
      tsum += pv; pb1[r] = (bf16)pv;
    }
    tsum += __shfl_xor(tsum, 32);
    lrow += tsum;
    // ---- PV (covers next-K latency) ----
    __builtin_amdgcn_s_setprio(1);
#pragma unroll
    for (int dt = 0; dt < 4; ++dt) {
      o[dt] = mfma32(va[2 * dt], pb0, o[dt]);
      o[dt] = mfma32(va[2 * dt + 1], pb1, o[dt]);
    }
    __builtin_amdgcn_s_setprio(0);
  }

  // ---- 3-way parity merge: plain sums (fixed m). l parked in own dead buffer. ----
  if (hi == 0) ((float*)(smem + ws * 16384 + 16128))[lq] = lrow;
  __syncthreads();   // drains vmcnt then barrier; staging LDS now dead
  float lgv = 0.f;
  if (ws == 0)
    lgv = ((float*)(smem + 16128))[lq]
        + ((float*)(smem + 16384 + 16128))[lq]
        + ((float*)(smem + 32768 + 16128))[lq];
  __builtin_amdgcn_sched_barrier(0);   // keep l reads before Obf overwrites
  if (ws == 0) {
#pragma unroll
    for (int dt = 0; dt < 4; ++dt)
#pragma unroll
      for (int r = 0; r < 16; ++r) {
        const int d = dt * 32 + (r & 3) + 8 * (r >> 2) + 4 * hi;
        Obf[lq * 129 + d] = o[dt][r];
      }
    if (hi == 0) ((float*)(smem + 16512))[lq] = lgv;   // Lg (beyond Obf's 16508B)
  }
  __syncthreads();
  if (ws == 1) {
#pragma unroll
    for (int dt = 0; dt < 4; ++dt)
#pragma unroll
      for (int r = 0; r < 16; ++r) {
        const int d = dt * 32 + (r & 3) + 8 * (r >> 2) + 4 * hi;
        Obf[lq * 129 + d] += o[dt][r];
      }
  }
  __syncthreads();
  if (ws == 2) {
#pragma unroll
    for (int dt = 0; dt < 4; ++dt)
#pragma unroll
      for (int r = 0; r < 16; ++r) {
        const int d = dt * 32 + (r & 3) + 8 * (r >> 2) + 4 * hi;
        Obf[lq * 129 + d] += o[dt][r];
      }
  }
  __syncthreads();
  // ---- epilogue: first 128 threads, row = tid>>2, 32 d each ----
  if (tid < 128) {
    const int row = tid >> 2;
    const int d0 = (tid & 3) * 32;
    const float linv = 1.0f / ((float*)(smem + 16512))[row];
    const float* orow = Obf + row * 129 + d0;
    bf16* dst = ctx + (size_t)(q0 + row) * (NH * HD) + h * HD + d0;
#pragma unroll
    for (int j = 0; j < 4; ++j) {
      bf16x8 pk;
#pragma unroll
      for (int e = 0; e < 8; ++e) pk[e] = (bf16)(orow[j * 8 + e] * linv);
      *reinterpret_cast<bf16x8*>(dst + j * 8) = pk;
    }
  }
}

extern "C" void kernel_launch(void* const* d_in, const int* in_sizes, int n_in,
                              void* d_out, int out_size, void* d_ws, size_t ws_size,
                              hipStream_t stream)
{
  const float* x       = (const float*)d_in[0];
  const float* w_qkv   = (const float*)d_in[1];
  const float* w_dense = (const float*)d_in[2];
  float* out = (float*)d_out;

  char* ws = (char*)d_ws;
  size_t off = 0;
  bf16* xb    = (bf16*)(ws + off); off += (size_t)S_LEN * EMB * 2;
  bf16* wqkvb = (bf16*)(ws + off); off += (size_t)FQKV * EMB * 2;
  bf16* wdb   = (bf16*)(ws + off); off += (size_t)EMB * EMB * 2;
  bf16* qbuf  = (bf16*)(ws + off); off += (size_t)NH  * S_LEN * HD * 2;
  bf16* kbuf  = (bf16*)(ws + off); off += (size_t)NKV * S_LEN * HD * 2;
  bf16* vfbuf = (bf16*)(ws + off); off += (size_t)NKV * HD * S_LEN * 2;
  bf16* ctxb  = (bf16*)(ws + off); off += (size_t)S_LEN * NH * HD * 2;
  float2* rtab = (float2*)(ws + off); off += (size_t)S_LEN * 64 * sizeof(float2);
  (void)ws_size; (void)in_sizes; (void)n_in; (void)out_size;

  rope_init<<<512, 256, 0, stream>>>(rtab);

  cvt3_kernel<<<2048, 256, 0, stream>>>(
      x, xb, S_LEN * EMB / 4,
      w_qkv, wqkvb, FQKV * EMB / 4,
      w_dense, wdb, EMB * EMB / 4);

  gemm_bt<64, 128><<<dim3(FQKV / 128, S_LEN / 64), 256, 0, stream>>>(
      xb, wqkvb, S_LEN, FQKV, EMB, 0, qbuf, kbuf, vfbuf, nullptr, rtab);

  attn_kernel<<<1024, 192, 0, stream>>>(qbuf, kbuf, vfbuf, ctxb);

  gemm_bt<128, 64><<<dim3(EMB / 64, S_LEN / 128), 256, 0, stream>>>(
      ctxb, wdb, S_LEN, EMB, NH * HD, 1, nullptr, nullptr, nullptr, out, rtab);
}

// Round 20
// 117.874 us; speedup vs baseline: 1.0705x; 1.0705x over previous
//
#include <hip/hip_runtime.h>
#include <hip/hip_bf16.h>
#include <math.h>

typedef __bf16 bf16;
typedef __bf16 bf16x4 __attribute__((ext_vector_type(4)));
typedef __bf16 bf16x8 __attribute__((ext_vector_type(8)));
typedef float  f32x4  __attribute__((ext_vector_type(4)));
typedef float  f32x16 __attribute__((ext_vector_type(16)));

#define S_LEN 2048
#define EMB   2048
#define NH    16
#define NKV   4
#define HD    128
#define FQKV  3072  /* NH*HD + 2*NKV*HD */

__device__ __forceinline__ f32x4 mfma16(bf16x8 a, bf16x8 b, f32x4 c) {
  return __builtin_amdgcn_mfma_f32_16x16x32_bf16(a, b, c, 0, 0, 0);
}
__device__ __forceinline__ f32x16 mfma32(bf16x8 a, bf16x8 b, f32x16 c) {
  return __builtin_amdgcn_mfma_f32_32x32x16_bf16(a, b, c, 0, 0, 0);
}
__device__ __forceinline__ f32x16 zero16() {
  f32x16 v;
#pragma unroll
  for (int i = 0; i < 16; ++i) v[i] = 0.f;
  return v;
}

// ------- fused f32 -> bf16 convert (all three inputs) + RoPE table init -------
__global__ void cvt3_kernel(const float* __restrict__ a, bf16* __restrict__ ab, int na4,
                            const float* __restrict__ b, bf16* __restrict__ bb, int nb4,
                            const float* __restrict__ c, bf16* __restrict__ cb, int nc4,
                            float2* __restrict__ rt) {
  const int gid = blockIdx.x * blockDim.x + threadIdx.x;
  const int stride = gridDim.x * blockDim.x;
  const int total = na4 + nb4 + nc4;
  for (int i = gid; i < total; i += stride) {
    const float* src; bf16* dst; int j = i;
    if (j < na4)            { src = a; dst = ab; }
    else if (j < na4 + nb4) { j -= na4; src = b; dst = bb; }
    else                    { j -= na4 + nb4; src = c; dst = cb; }
    float4 v = reinterpret_cast<const float4*>(src)[j];
    bf16x4 o;
    o[0] = (bf16)v.x; o[1] = (bf16)v.y; o[2] = (bf16)v.z; o[3] = (bf16)v.w;
    reinterpret_cast<bf16x4*>(dst)[j] = o;
  }
  for (int i = gid; i < S_LEN * 64; i += stride) {   // RoPE table
    const int spos = i >> 6, f = i & 63;
    const float inv = exp2f(-(float)f * (13.287712379549449f / 64.0f)); // 10000^(-f/64)
    float s, cc;
    sincosf((float)spos * inv, &s, &cc);
    rt[i] = make_float2(cc, s);
  }
}

// ---------------- GEMM: C[M][N] = A[M][K] * B[N][K]^T, tile BM x BN ----------------
// BM=64,BN=128 mode 0 (QKV): 768 blocks = 3/CU. Fused RoPE/split epilogue,
//   Q/K/V in fragment-ready TILED layouts; indices derived from absolute spos.
// BM=64,BN=64 mode 1 (dense): 1024 blocks = 4/CU (16 waves/CU), plain f32 store.
template<int BM, int BN>
__global__ __launch_bounds__(256, ((BM == 64 && BN == 64) ? 4 : (BM == 64 ? 3 : 2)))
void gemm_bt(
    const bf16* __restrict__ A, const bf16* __restrict__ B,
    int M, int N, int K, int mode,
    bf16* __restrict__ qb, bf16* __restrict__ kb, bf16* __restrict__ vtb,
    float* __restrict__ outf, const float2* __restrict__ rt)
{
  constexpr int NFR = BN / 16;      // N fragments per wave
  constexpr int MR  = BM / 4;       // rows per wave
  constexpr int MT  = MR / 16;      // M fragments per wave
  __shared__ __align__(16) bf16 As[BM * 64];
  __shared__ __align__(16) bf16 Bs[BN * 64];
  const int tid = threadIdx.x;
  const int w  = tid >> 6;
  const int l  = tid & 63;
  const int li = l & 15, lh = l >> 4;
  const int m0 = blockIdx.y * BM, n0 = blockIdx.x * BN;

  f32x4 acc[MT][NFR];
#pragma unroll
  for (int i = 0; i < MT; ++i)
#pragma unroll
    for (int j = 0; j < NFR; ++j) acc[i][j] = f32x4{0.f, 0.f, 0.f, 0.f};

  const int srow = l >> 3;   // row within an 8-row staging group
  const int schk = l & 7;    // 16B chunk within a 64-col row

  for (int k0 = 0; k0 < K; k0 += 64) {
#pragma unroll
    for (int i = 0; i < BM / 32; ++i) {    // A: BM rows
      const int row = i * 32 + w * 8 + srow;
      const int sch = schk ^ (row & 7);
      const bf16* ga = A + (size_t)(m0 + row) * K + (k0 + sch * 8);
      bf16* la = As + (i * 32 + w * 8) * 64;
      __builtin_amdgcn_global_load_lds((const __attribute__((address_space(1))) void*)ga,
                                       (__attribute__((address_space(3))) void*)la, 16, 0, 0);
    }
#pragma unroll
    for (int i = 0; i < BN / 32; ++i) {    // B: BN rows
      const int row = i * 32 + w * 8 + srow;
      const int sch = schk ^ (row & 7);
      const bf16* gb = B + (size_t)(n0 + row) * K + (k0 + sch * 8);
      bf16* lb = Bs + (i * 32 + w * 8) * 64;
      __builtin_amdgcn_global_load_lds((const __attribute__((address_space(1))) void*)gb,
                                       (__attribute__((address_space(3))) void*)lb, 16, 0, 0);
    }
    __syncthreads();
#pragma unroll
    for (int kc = 0; kc < 2; ++kc) {
      bf16x8 afr[MT], bfr[NFR];
#pragma unroll
      for (int mt = 0; mt < MT; ++mt) {
        const int mr = w * MR + mt * 16 + li;
        const int c  = (kc * 4 + lh) ^ (mr & 7);
        afr[mt] = *reinterpret_cast<const bf16x8*>((const char*)As + mr * 128 + c * 16);
      }
#pragma unroll
      for (int nt = 0; nt < NFR; ++nt) {
        const int nr = nt * 16 + li;
        const int c  = (kc * 4 + lh) ^ (nr & 7);
        bfr[nt] = *reinterpret_cast<const bf16x8*>((const char*)Bs + nr * 128 + c * 16);
      }
#pragma unroll
      for (int mt = 0; mt < MT; ++mt)
#pragma unroll
        for (int nt = 0; nt < NFR; ++nt)
          acc[mt][nt] = mfma16(afr[mt], bfr[nt], acc[mt][nt]);
    }
    __syncthreads();
  }

  // ---- epilogue ----
  if (mode == 1) {
#pragma unroll
    for (int mt = 0; mt < MT; ++mt)
#pragma unroll
      for (int nt = 0; nt < NFR; ++nt)
#pragma unroll
        for (int r = 0; r < 4; ++r) {
          const int sr = m0 + w * MR + mt * 16 + lh * 4 + r;
          const int sc = n0 + nt * 16 + li;
          outf[(size_t)sr * N + sc] = acc[mt][nt][r];
        }
  } else {
    int seg, hh;
    if (n0 < NH * HD)             { seg = 0; hh = n0 >> 7; }
    else if (n0 < (NH + NKV) * HD){ seg = 1; hh = (n0 - NH * HD) >> 7; }
    else                          { seg = 2; hh = (n0 - (NH + NKV) * HD) >> 7; }

    if (seg == 2) {
      // V tiled store; all indices from absolute spos (S0 = spos of r=0).
#pragma unroll
      for (int mt = 0; mt < MT; ++mt) {
        const int S0 = m0 + w * MR + mt * 16 + lh * 4;
        const int T  = S0 >> 5;
        const int qp = (S0 & 31) >> 2;
        const int jj = (qp >> 2) & 1, hiv = qp & 1, ebase = 4 * ((qp >> 1) & 1);
        bf16* vdst = vtb + (size_t)hh * S_LEN * HD + (size_t)T * 4096;
#pragma unroll
        for (int nt = 0; nt < 8; ++nt) {
          const int dt = nt >> 1;
          const int lqv = (nt & 1) * 16 + li;
          bf16x4 pk;
#pragma unroll
          for (int r = 0; r < 4; ++r) pk[r] = (bf16)acc[mt][nt][r];
          *reinterpret_cast<bf16x4*>(
              vdst + ((dt * 2 + jj) * 2 + hiv) * 256 + lqv * 8 + ebase) = pk;
        }
      }
    } else {  // Q or K: RoPE (table-driven; 1/sqrt(D) folded into Q), tiled store
      bf16* dstb = (seg == 0) ? (qb + (size_t)hh * S_LEN * HD)
                              : (kb + (size_t)hh * S_LEN * HD);
      const float qscale = (seg == 0) ? 0.08838834764831845f : 1.0f;
      const int hi2 = li >> 3, e2 = li & 7;
#pragma unroll
      for (int mt = 0; mt < MT; ++mt)
#pragma unroll
        for (int r = 0; r < 4; ++r) {
          const int spos = m0 + w * MR + mt * 16 + lh * 4 + r;
          const int T    = spos >> 5;
          const int lqr  = spos & 31;
          bf16* dst = dstb + (size_t)T * 4096;
          float cs[4], sn[4];
#pragma unroll
          for (int j = 0; j < 4; ++j) {
            const float2 t = rt[spos * 64 + j * 16 + li];
            cs[j] = t.x; sn[j] = t.y;
          }
#pragma unroll
          for (int nt = 0; nt < 8; ++nt) {
            const int j = nt & 3;
            const float x = acc[mt][nt][r];
            const float prt = acc[mt][nt ^ 4][r];
            const float rot = (nt < 4) ? -prt : prt;
            const float y = (x * cs[j] + rot * sn[j]) * qscale;
            dst[(nt * 2 + hi2) * 256 + lqr * 8 + e2] = (bf16)y;
          }
        }
    }
  }
}

// ---------------- flash attention: counted-vmcnt split-stage pipeline (r18) ----------------
// 1024 blocks x 128 thr. Block (qt, h) owns 32 q-rows; its 2 waves split KV by
// parity. K and V are SEPARATE pipeline stages with FIFO-counted waits (never
// drain to 0 mid-loop). Fixed-m softmax (scores O(5)). LDS 32KB.
__global__ __launch_bounds__(128, 2) void attn_kernel(
    const bf16* __restrict__ qb, const bf16* __restrict__ kb, const bf16* __restrict__ vtb,
    bf16* __restrict__ ctx)
{
  __shared__ __align__(16) char smem[32768];   // 2 x 16KB wave K/V bufs; aliased Obf/Lg

  const int tid = threadIdx.x;
  const int ws = tid >> 6;      // wave id = kv parity
  const int l  = tid & 63;
  const int lq = l & 31;
  const int hi = l >> 5;
  const int b  = (int)blockIdx.x;
  const int layer = b >> 8, idx = b & 255;
  const int h    = idx & 15;
  const int base = idx >> 4;
  const int qt   = (layer == 0) ? (63 - base)
                 : (layer == 1) ? (32 + base)
                 : (layer == 2) ? (31 - base) : base;
  const int q0 = qt * 32;
  const int kh = h >> 2;

  bf16* Kbuf = (bf16*)(smem + ws * 16384);          // 8 KB
  bf16* Vbuf = (bf16*)(smem + ws * 16384 + 8192);   // 8 KB
  float* Obf = (float*)smem;                        // [32][129] f32, epilogue only

  const bf16* Qh = qb + (size_t)h * S_LEN * HD;
  const bf16* Kh = kb + (size_t)kh * S_LEN * HD;
  const bf16* Vh = vtb + (size_t)kh * S_LEN * HD;

  const float L2E = 1.4426950408889634f;
  const float BIG = -3.0e38f;

  // hoist Q fragments (coalesced 1KB loads from tiled layout)
  const bf16* qtile = Qh + (size_t)qt * 4096;
  bf16x8 qfr[8];
#pragma unroll
  for (int kc = 0; kc < 8; ++kc)
    qfr[kc] = *reinterpret_cast<const bf16x8*>(qtile + (kc * 2 + hi) * 256 + lq * 8);

  f32x16 o[4];
#pragma unroll
  for (int dt = 0; dt < 4; ++dt) o[dt] = zero16();
  float lrow = 0.f;

  // ---- prologue: stage this wave's first tile (K then V: FIFO order) ----
  if (ws <= qt) {
    const bf16* ksrc = Kh + (size_t)ws * 4096 + l * 8;
    const bf16* vsrc = Vh + (size_t)ws * 4096 + l * 8;
#pragma unroll
    for (int c = 0; c < 8; ++c)
      __builtin_amdgcn_global_load_lds(
          (const __attribute__((address_space(1))) void*)(ksrc + c * 512),
          (__attribute__((address_space(3))) void*)(Kbuf + c * 512), 16, 0, 0);
#pragma unroll
    for (int c = 0; c < 8; ++c)
      __builtin_amdgcn_global_load_lds(
          (const __attribute__((address_space(1))) void*)(vsrc + c * 512),
          (__attribute__((address_space(3))) void*)(Vbuf + c * 512), 16, 0, 0);
  }

  for (int t = ws; t <= qt; t += 2) {
    const int tn = (t + 2 <= qt) ? (t + 2) : qt;   // clamped prefetch (uniform counts)
    // ---- K stage: wait K (V still in flight), read frags, refill K ----
    asm volatile("s_waitcnt vmcnt(8)" ::: "memory");
    __builtin_amdgcn_sched_barrier(0);
    bf16x8 kf[8];
#pragma unroll
    for (int kc = 0; kc < 8; ++kc)
      kf[kc] = *reinterpret_cast<const bf16x8*>(Kbuf + (kc * 2 + hi) * 256 + lq * 8);
    asm volatile("s_waitcnt lgkmcnt(0)" ::: "memory");
    __builtin_amdgcn_sched_barrier(0);
    {
      const bf16* ksrc = Kh + (size_t)tn * 4096 + l * 8;
#pragma unroll
      for (int c = 0; c < 8; ++c)
        __builtin_amdgcn_global_load_lds(
            (const __attribute__((address_space(1))) void*)(ksrc + c * 512),
            (__attribute__((address_space(3))) void*)(Kbuf + c * 512), 16, 0, 0);
    }
    // ---- QK^T: S^T[kv][q], two chains of 4 (covers V's remaining latency) ----
    f32x16 sa = zero16(), sb = zero16();
    __builtin_amdgcn_s_setprio(1);
#pragma unroll
    for (int kc = 0; kc < 4; ++kc) {
      sa = mfma32(kf[kc], qfr[kc], sa);
      sb = mfma32(kf[kc + 4], qfr[kc + 4], sb);
    }
    __builtin_amdgcn_s_setprio(0);
    f32x16 s = sa + sb;
    // ---- V stage: wait V (next-K in flight), read frags, refill V ----
    asm volatile("s_waitcnt vmcnt(8)" ::: "memory");
    __builtin_amdgcn_sched_barrier(0);
    bf16x8 va[8];
#pragma unroll
    for (int sv = 0; sv < 8; ++sv)
      va[sv] = *reinterpret_cast<const bf16x8*>(Vbuf + (sv * 2 + hi) * 256 + lq * 8);
    asm volatile("s_waitcnt lgkmcnt(0)" ::: "memory");
    __builtin_amdgcn_sched_barrier(0);
    {
      const bf16* vsrc = Vh + (size_t)tn * 4096 + l * 8;
#pragma unroll
      for (int c = 0; c < 8; ++c)
        __builtin_amdgcn_global_load_lds(
            (const __attribute__((address_space(1))) void*)(vsrc + c * 512),
            (__attribute__((address_space(3))) void*)(Vbuf + c * 512), 16, 0, 0);
    }
    // ---- causal mask (diagonal tile only) ----
    if (t == qt) {
      const int q = q0 + lq;
#pragma unroll
      for (int r = 0; r < 16; ++r) {
        const int kvv = (r & 3) + 8 * (r >> 2) + 4 * hi;
        if (t * 32 + kvv > q) s[r] = BIG;
      }
    }
    // ---- fixed-m softmax: P = exp2(s*L2E), no max tracking, no rescale ----
    bf16x8 pb0, pb1;
    float tsum = 0.f;
#pragma unroll
    for (int r = 0; r < 8; ++r) {
      const float pv = exp2f(s[r] * L2E);
      tsum += pv; pb0[r] = (bf16)pv;
    }
#pragma unroll
    for (int r = 0; r < 8; ++r) {
      const float pv = exp2f(s[8 + r] * L2E);
      tsum += pv; pb1[r] = (bf16)pv;
    }
    tsum += __shfl_xor(tsum, 32);
    lrow += tsum;
    // ---- PV (covers next-K latency) ----
    __builtin_amdgcn_s_setprio(1);
#pragma unroll
    for (int dt = 0; dt < 4; ++dt) {
      o[dt] = mfma32(va[2 * dt], pb0, o[dt]);
      o[dt] = mfma32(va[2 * dt + 1], pb1, o[dt]);
    }
    __builtin_amdgcn_s_setprio(0);
  }

  // ---- 2-way parity merge: plain sums (fixed m). l parked in own dead buffer. ----
  if (hi == 0) ((float*)(smem + ws * 16384 + 16128))[lq] = lrow;
  __syncthreads();   // drains vmcnt then barrier; staging LDS now dead
  float lgv = 0.f;
  if (ws == 0)
    lgv = ((float*)(smem + 16128))[lq] + ((float*)(smem + 16384 + 16128))[lq];
  __builtin_amdgcn_sched_barrier(0);   // keep l reads before Obf overwrites
  if (ws == 0) {
#pragma unroll
    for (int dt = 0; dt < 4; ++dt)
#pragma unroll
      for (int r = 0; r < 16; ++r) {
        const int d = dt * 32 + (r & 3) + 8 * (r >> 2) + 4 * hi;
        Obf[lq * 129 + d] = o[dt][r];
      }
    if (hi == 0) ((float*)(smem + 16512))[lq] = lgv;   // Lg (beyond Obf's 16508B)
  }
  __syncthreads();
  if (ws == 1) {
#pragma unroll
    for (int dt = 0; dt < 4; ++dt)
#pragma unroll
      for (int r = 0; r < 16; ++r) {
        const int d = dt * 32 + (r & 3) + 8 * (r >> 2) + 4 * hi;
        Obf[lq * 129 + d] += o[dt][r];
      }
  }
  __syncthreads();
  // ---- epilogue: 128 threads, row = tid>>2, 32 d each ----
  {
    const int row = tid >> 2;
    const int d0 = (tid & 3) * 32;
    const float linv = 1.0f / ((float*)(smem + 16512))[row];
    const float* orow = Obf + row * 129 + d0;
    bf16* dst = ctx + (size_t)(q0 + row) * (NH * HD) + h * HD + d0;
#pragma unroll
    for (int j = 0; j < 4; ++j) {
      bf16x8 pk;
#pragma unroll
      for (int e = 0; e < 8; ++e) pk[e] = (bf16)(orow[j * 8 + e] * linv);
      *reinterpret_cast<bf16x8*>(dst + j * 8) = pk;
    }
  }
}

extern "C" void kernel_launch(void* const* d_in, const int* in_sizes, int n_in,
                              void* d_out, int out_size, void* d_ws, size_t ws_size,
                              hipStream_t stream)
{
  const float* x       = (const float*)d_in[0];
  const float* w_qkv   = (const float*)d_in[1];
  const float* w_dense = (const float*)d_in[2];
  float* out = (float*)d_out;

  char* ws = (char*)d_ws;
  size_t off = 0;
  bf16* xb    = (bf16*)(ws + off); off += (size_t)S_LEN * EMB * 2;
  bf16* wqkvb = (bf16*)(ws + off); off += (size_t)FQKV * EMB * 2;
  bf16* wdb   = (bf16*)(ws + off); off += (size_t)EMB * EMB * 2;
  bf16* qbuf  = (bf16*)(ws + off); off += (size_t)NH  * S_LEN * HD * 2;
  bf16* kbuf  = (bf16*)(ws + off); off += (size_t)NKV * S_LEN * HD * 2;
  bf16* vfbuf = (bf16*)(ws + off); off += (size_t)NKV * HD * S_LEN * 2;
  bf16* ctxb  = (bf16*)(ws + off); off += (size_t)S_LEN * NH * HD * 2;
  float2* rtab = (float2*)(ws + off); off += (size_t)S_LEN * 64 * sizeof(float2);
  (void)ws_size; (void)in_sizes; (void)n_in; (void)out_size;

  cvt3_kernel<<<2048, 256, 0, stream>>>(
      x, xb, S_LEN * EMB / 4,
      w_qkv, wqkvb, FQKV * EMB / 4,
      w_dense, wdb, EMB * EMB / 4, rtab);

  gemm_bt<64, 128><<<dim3(FQKV / 128, S_LEN / 64), 256, 0, stream>>>(
      xb, wqkvb, S_LEN, FQKV, EMB, 0, qbuf, kbuf, vfbuf, nullptr, rtab);

  attn_kernel<<<1024, 128, 0, stream>>>(qbuf, kbuf, vfbuf, ctxb);

  gemm_bt<64, 64><<<dim3(EMB / 64, S_LEN / 64), 256, 0, stream>>>(
      ctxb, wdb, S_LEN, EMB, NH * HD, 1, nullptr, nullptr, nullptr, out, rtab);
}